// Round 9
// baseline (433.763 us; speedup 1.0000x reference)
//
#include <hip/hip_runtime.h>
#include <hip/hip_bf16.h>
#include <stdint.h>
#include <string.h>

typedef unsigned short u16;
typedef unsigned int u32;
typedef __bf16 bf16x8 __attribute__((ext_vector_type(8)));
typedef float f32x4 __attribute__((ext_vector_type(4)));

// Problem constants
#define NB 4
#define NC 64
#define NH 8
#define NL 2048
#define HC 512   // H*C

// Workspace layout (bytes).
#define XT_OFF  ((size_t)0)          // bf16 xT[b][l][c]            1 MB
#define WM_OFF  ((size_t)1 << 20)    // bf16 Wm[tns][d][o][c]       576 KB
#define PBM_OFF ((size_t)2 << 20)    // f32  pbm[tns][o]            6 KB
#define V_OFF   ((size_t)4 << 20)    // bf16 v[b][o][l]             8 MB
#define QT_OFF  ((size_t)12 << 20)   // bf16 qT[bh][l][c]           8 MB
#define KT_OFF  ((size_t)20 << 20)   // bf16 kT[bh][l][c]           8 MB

#define LP 68   // padded LDS row stride (u16); measured 0 bank conflicts (R8)

#if __has_builtin(__builtin_amdgcn_exp2f)
#define EXP2F __builtin_amdgcn_exp2f
#else
#define EXP2F exp2f
#endif

static __device__ __forceinline__ u16 f2bfu(float f) {
  union { float f; unsigned int i; } x; x.f = f;
  unsigned int i = x.i;
  return (u16)((i + 0x7fffu + ((i >> 16) & 1u)) >> 16);  // RTE, finite inputs
}
static __device__ __forceinline__ u32 pk2(float a, float b) {
  float2 f; f.x = a; f.y = b;
  __hip_bfloat162 h = __float22bfloat162_rn(f);   // packed cvt on gfx950
  u32 w; __builtin_memcpy(&w, &h, 4); return w;
}
static __device__ __forceinline__ bf16x8 ld_bf8(const u16* p) {
  bf16x8 v; __builtin_memcpy(&v, p, 16); return v;
}

// ---------------------------------------------------------------------------
// Kernel P: fused prep. Block ranges:
//  [0,512)    init_out: out[b,c,l] = ub[c]
//  [512,902)  prep_w: merged conv weights + folded bias
//  [902,1030) prep_x: x[b][c][l] f32 -> xT[b][l][c] bf16
// ---------------------------------------------------------------------------
__global__ __launch_bounds__(256) void prep_all(
    const float* __restrict__ x,
    const float* __restrict__ qdw, const float* __restrict__ qdb,
    const float* __restrict__ qpw, const float* __restrict__ qpb,
    const float* __restrict__ kdw, const float* __restrict__ kdb,
    const float* __restrict__ kpw, const float* __restrict__ kpb,
    const float* __restrict__ vdw, const float* __restrict__ vdb,
    const float* __restrict__ vpw, const float* __restrict__ vpb,
    const float* __restrict__ ub,
    u16* __restrict__ Wm, float* __restrict__ pbm,
    u16* __restrict__ xT, float* __restrict__ out)
{
  __shared__ __align__(16) u16 T[64 * LP];
  int bx = blockIdx.x;
  int tid = threadIdx.x;

  if (bx < 512) {
    int i4 = bx * 256 + tid;     // float4 index
    int c = (i4 >> 9) & 63;
    float f = ub[c];
    float4 v = {f, f, f, f};
    ((float4*)out)[i4] = v;
    return;
  }
  if (bx < 902) {
    int idx = (bx - 512) * 256 + tid;
    if (idx < 98304) {
      int tns = idx >> 15, r = idx & 32767, o = r >> 6, c = r & 63;
      const float* dw = (tns == 0) ? qdw : (tns == 1) ? kdw : vdw;
      const float* pw = (tns == 0) ? qpw : (tns == 1) ? kpw : vpw;
      float s = (tns == 0) ? 0.35355339059327373f * 1.4426950408889634f
              : (tns == 1) ? 0.35355339059327373f : 1.0f;
      float w = pw[o * 64 + c] * s;
#pragma unroll
      for (int d = 0; d < 3; ++d)
        Wm[((size_t)(tns * 3 + d) * 512 + o) * 64 + c] = f2bfu(w * dw[c * 3 + d]);
    } else {
      int i = idx - 98304;
      int tns = i >> 9, o = i & 511;
      const float* db = (tns == 0) ? qdb : (tns == 1) ? kdb : vdb;
      const float* pw = (tns == 0) ? qpw : (tns == 1) ? kpw : vpw;
      const float* pb = (tns == 0) ? qpb : (tns == 1) ? kpb : vpb;
      float s = (tns == 0) ? 0.35355339059327373f * 1.4426950408889634f
              : (tns == 1) ? 0.35355339059327373f : 1.0f;
      float bias = pb[o];
      for (int c = 0; c < 64; ++c) bias += pw[o * 64 + c] * db[c];
      pbm[i] = bias * s;
    }
    return;
  }
  // prep_x
  {
    int b2 = bx - 902;
    int lt = b2 & 31, b = b2 >> 5;
    {
      int c = tid & 63, ls = (tid >> 6) * 16;
      const float4* g = (const float4*)(x + ((size_t)b * NC + c) * NL + lt * 64 + ls);
      u16 tmp[16];
#pragma unroll
      for (int j4 = 0; j4 < 4; ++j4) {
        float4 f = g[j4];
        tmp[j4*4+0] = f2bfu(f.x); tmp[j4*4+1] = f2bfu(f.y);
        tmp[j4*4+2] = f2bfu(f.z); tmp[j4*4+3] = f2bfu(f.w);
      }
#pragma unroll
      for (int j = 0; j < 16; ++j) T[(ls + j) * LP + c] = tmp[j];
    }
    __syncthreads();
    {
      int r = tid >> 2, cs = (tid & 3) * 16;
      uint4 a = *(const uint4*)&T[r * LP + cs];
      uint4 b3 = *(const uint4*)&T[r * LP + cs + 8];
      u16* o = xT + ((size_t)b * NL + lt * 64 + r) * 64 + cs;
      *(uint4*)o = a;
      *(uint4*)(o + 8) = b3;
    }
  }
}

// ---------------------------------------------------------------------------
// Kernel 1: qkv via MFMA, 4 l-tiles per block, XS double-buffered, ONE
// barrier per tile (epilogue rows are wave-private -> no cross-wave hazard).
// grid = 4b * 3tns * 8och * 8 lgroups = 768 blocks; LDS ~53 KB -> 3/CU.
// ---------------------------------------------------------------------------
__global__ __launch_bounds__(256) void qkv_gemm(
    const u16* __restrict__ xT, const u16* __restrict__ Wm,
    const float* __restrict__ pbm,
    u16* __restrict__ v, u16* __restrict__ qT, u16* __restrict__ kT)
{
  __shared__ __align__(16) u16 WS[3][64 * LP];   // WS[d][o][c]
  __shared__ __align__(16) u16 XS[2][66 * LP];   // XS[buf][r][c], r0 = l0-1
  __shared__ __align__(16) u16 OS[64 * LP];      // epilogue staging (wave-private rows)

  int bx = blockIdx.x;
  int lg  = bx & 7;
  int och = (bx >> 3) & 7;
  int tmp = bx >> 6;
  int tns = tmp % 3;
  int b   = tmp / 3;

  int tid = threadIdx.x;
  int wave = tid >> 6, lane = tid & 63, quad = lane >> 4, l16 = lane & 15;
  const u16* xg = xT + (size_t)b * NL * 64;

  // stage merged weights once (o-chunk slice, 3 d-slices)
  {
    const u16* wg = Wm + ((size_t)(tns * 3) * 512 + och * 64) * 64;
#pragma unroll
    for (int it = 0; it < 6; ++it) {
      int s = tid + it * 256;
      int d = s >> 9, r = s & 511;
      int o = r >> 3, c4 = r & 7;
      uint4 w = *(const uint4*)(wg + ((size_t)d * 512 + o) * 64 + c4 * 8);
      *(uint4*)&WS[d][o * LP + c4 * 8] = w;
    }
  }

  // XS prefetch helpers: 528 uint4 slots (66 rows x 8), <=3 per thread
  int xr0 = tid >> 3,          xc0 = (tid & 7) * 8;
  int xr1 = (tid + 256) >> 3,  xc1 = xc0;
  int xr2 = (tid + 512) >> 3,  xc2 = xc0;
  uint4 R0, R1, R2;
  uint4 Z = {0, 0, 0, 0};

#define LOAD_XS(tt)                                                         \
  {                                                                         \
    int base = (lg * 4 + (tt)) * 64 - 1;                                    \
    int g0 = base + xr0, g1 = base + xr1, g2 = base + xr2;                  \
    R0 = ((unsigned)g0 < NL) ? *(const uint4*)(xg + (size_t)g0 * 64 + xc0) : Z; \
    R1 = ((unsigned)g1 < NL) ? *(const uint4*)(xg + (size_t)g1 * 64 + xc1) : Z; \
    if (tid < 16)                                                           \
      R2 = ((unsigned)g2 < NL) ? *(const uint4*)(xg + (size_t)g2 * 64 + xc2) : Z; \
  }
#define STORE_XS(bf)                                                        \
  {                                                                         \
    *(uint4*)&XS[bf][xr0 * LP + xc0] = R0;                                  \
    *(uint4*)&XS[bf][xr1 * LP + xc1] = R1;                                  \
    if (tid < 16) *(uint4*)&XS[bf][xr2 * LP + xc2] = R2;                    \
  }

  LOAD_XS(0); STORE_XS(0);
  LOAD_XS(1);
  __syncthreads();

  // bias regs + v-path hoisted A fragments (tile-invariant)
  float bias4[4];
  bf16x8 aw[3][2];
  if (tns == 2) {
    const float* pbt = pbm + tns * 512 + och * 64 + wave * 16;
#pragma unroll
    for (int rr = 0; rr < 4; ++rr) bias4[rr] = pbt[quad * 4 + rr];
#pragma unroll
    for (int d = 0; d < 3; ++d)
#pragma unroll
      for (int kh = 0; kh < 2; ++kh)
        aw[d][kh] = ld_bf8(&WS[d][(wave * 16 + l16) * LP + kh * 32 + quad * 8]);
  } else {
    const float* pbt = pbm + tns * 512 + och * 64;
#pragma unroll
    for (int nt = 0; nt < 4; ++nt) bias4[nt] = pbt[nt * 16 + l16];
  }

  for (int t = 0; t < 4; ++t) {
    int cur = t & 1;
    f32x4 acc[4] = {{0,0,0,0},{0,0,0,0},{0,0,0,0},{0,0,0,0}};

    if (tns == 2) {
#pragma unroll
      for (int nt = 0; nt < 4; ++nt)
#pragma unroll
        for (int d = 0; d < 3; ++d)
#pragma unroll
          for (int kh = 0; kh < 2; ++kh) {
            bf16x8 bx8 = ld_bf8(&XS[cur][(nt * 16 + l16 + d) * LP + kh * 32 + quad * 8]);
            acc[nt] = __builtin_amdgcn_mfma_f32_16x16x32_bf16(aw[d][kh], bx8, acc[nt], 0, 0, 0);
          }
    } else {
      bf16x8 ax[3][2];
#pragma unroll
      for (int d = 0; d < 3; ++d)
#pragma unroll
        for (int kh = 0; kh < 2; ++kh)
          ax[d][kh] = ld_bf8(&XS[cur][(wave * 16 + l16 + d) * LP + kh * 32 + quad * 8]);
#pragma unroll
      for (int nt = 0; nt < 4; ++nt)
#pragma unroll
        for (int d = 0; d < 3; ++d)
#pragma unroll
          for (int kh = 0; kh < 2; ++kh) {
            bf16x8 bw = ld_bf8(&WS[d][(nt * 16 + l16) * LP + kh * 32 + quad * 8]);
            acc[nt] = __builtin_amdgcn_mfma_f32_16x16x32_bf16(ax[d][kh], bw, acc[nt], 0, 0, 0);
          }
    }

    if (t < 3) { STORE_XS((t + 1) & 1); if (t < 2) LOAD_XS(t + 2); }
    __syncthreads();   // the ONLY barrier per tile: XS[next] ready

    // epilogue: wave-private OS rows (wave w owns rows w*16..w*16+15) ->
    // intra-wave lgkm ordering suffices, no barrier.
    if (tns == 2) {
#pragma unroll
      for (int nt = 0; nt < 4; ++nt)
#pragma unroll
        for (int rr = 0; rr < 4; ++rr)
          OS[(wave * 16 + quad * 4 + rr) * LP + nt * 16 + l16] =
              f2bfu(acc[nt][rr] + bias4[rr]);
    } else {
#pragma unroll
      for (int nt = 0; nt < 4; ++nt)
#pragma unroll
        for (int rr = 0; rr < 4; ++rr)
          OS[(wave * 16 + quad * 4 + rr) * LP + nt * 16 + l16] =
              f2bfu(acc[nt][rr] + bias4[nt]);
    }

    // coalesced store of this wave's own 16 rows: 4 lanes per row, 2 uint4
    {
      int lt = lg * 4 + t;
      int r = wave * 16 + (lane >> 2), ck = (lane & 3) * 16;
      uint4 a = *(const uint4*)&OS[r * LP + ck];
      uint4 b2 = *(const uint4*)&OS[r * LP + ck + 8];
      u16* gp;
      if (tns == 2)
        gp = v + ((size_t)(b * HC + och * 64 + r)) * NL + lt * 64 + ck;
      else {
        u16* dst = (tns == 0) ? qT : kT;
        gp = dst + ((size_t)(b * 8 + och) * NL + lt * 64 + r) * 64 + ck;
      }
      *(uint4*)gp = a;
      *(uint4*)(gp + 8) = b2;
    }
  }
#undef LOAD_XS
#undef STORE_XS
}

// ---------------------------------------------------------------------------
// Kernel 2: flash attention + fused unify. 128-thread (2-wave) blocks, 64q
// per block (32q/wave), grid 512 per dispatch x 2 dispatches (bh halves —
// halves each dispatch for top-5 visibility of hidden kernels).
// Small barrier domain: each __syncthreads syncs only 2 waves; 4 independent
// blocks/CU overlap each other's barrier drains (R8's 4-wave barriers were
// the stall: 67us vs ~24us LDS floor, nothing saturated).
// LDS ~30.4 KB. Q fragments read directly from global (no Q LDS).
// ---------------------------------------------------------------------------
__global__ __launch_bounds__(128) void attn_kernel(
    const u16* __restrict__ qT, const u16* __restrict__ kT,
    const u16* __restrict__ vg, const float* __restrict__ uw,
    float* __restrict__ outg, int bh0)
{
  __shared__ __align__(16) u16 Kt[64 * LP];      // Kt[key][c]
  __shared__ __align__(16) u16 Vt[64 * LP];      // Vt[c][key]
  __shared__ __align__(16) u16 UW[64 * LP];      // UW[c][c']
  __shared__ __align__(16) u16 PB[2][16 * LP];   // per-wave P / OT scratch

  int bx = blockIdx.x;
  int qt = bx & 31, bh = (bx >> 5) + bh0;
  int b = bh >> 3, h = bh & 7;
  int tid = threadIdx.x;
  int wave = tid >> 6, lane = tid & 63, quad = lane >> 4, l16 = lane & 15;

  const u16* Qh = qT + (size_t)bh * NL * 64;
  const u16* Kh = kT + (size_t)bh * NL * 64;
  const u16* Vh = vg + ((size_t)(b * HC + h * NC)) * NL;
  int q0 = qt * 64;

  // stage UW head slice as bf16: UW[c][c'] = uw[c*512 + h*64 + c']
  {
    int r = tid >> 1, cs = (tid & 1) * 32;
    const float4* s = (const float4*)(uw + (size_t)r * HC + h * 64 + cs);
#pragma unroll
    for (int j = 0; j < 8; ++j) {
      float4 w = s[j];
      u16* d = &UW[r * LP + cs + j * 4];
      d[0] = f2bfu(w.x); d[1] = f2bfu(w.y); d[2] = f2bfu(w.z); d[3] = f2bfu(w.w);
    }
  }

  // Q fragments for this wave's 32 queries, straight from global (qT[l][c])
  bf16x8 bq[2][2];
#pragma unroll
  for (int t = 0; t < 2; ++t)
#pragma unroll
    for (int kh = 0; kh < 2; ++kh)
      bq[t][kh] = ld_bf8(Qh + (size_t)(q0 + wave * 32 + t * 16 + l16) * 64
                         + kh * 32 + quad * 8);

  f32x4 o[2][4];
#pragma unroll
  for (int t = 0; t < 2; ++t)
#pragma unroll
    for (int ct = 0; ct < 4; ++ct) o[t][ct] = (f32x4){0, 0, 0, 0};
  float l_part[2] = {0.f, 0.f};

  // K/V staging: 512 uint4 slots each, 4 per thread
  uint4 kr[4], vr[4];
#define LOADKV(kt)                                                          \
  _Pragma("unroll")                                                         \
  for (int it = 0; it < 4; ++it) {                                          \
    int s = it * 128 + tid; int r = s >> 3, c = (s & 7) * 8;                \
    kr[it] = *(const uint4*)(Kh + (size_t)((kt) + r) * 64 + c);             \
    vr[it] = *(const uint4*)(Vh + (size_t)r * NL + (kt) + c);               \
  }

  LOADKV(0);

  u16* Pw = &PB[wave][0];

  for (int i = 0; i < 32; ++i) {
    __syncthreads();   // prev iter LDS reads done (2-wave scope)
#pragma unroll
    for (int it = 0; it < 4; ++it) {
      int s = it * 128 + tid; int r = s >> 3, c = (s & 7) * 8;
      *(uint4*)&Kt[r * LP + c] = kr[it];
      *(uint4*)&Vt[r * LP + c] = vr[it];
    }
    __syncthreads();
    if (i < 31) LOADKV((i + 1) * 64);

    // K and V fragments once per wave (reused for both q sub-tiles)
    bf16x8 ak[4][2], av[4][2];
#pragma unroll
    for (int j = 0; j < 4; ++j)
#pragma unroll
      for (int kh = 0; kh < 2; ++kh) {
        ak[j][kh] = ld_bf8(&Kt[(j * 16 + l16) * LP + kh * 32 + quad * 8]);
        av[j][kh] = ld_bf8(&Vt[(j * 16 + l16) * LP + kh * 32 + quad * 8]);
      }

#pragma unroll
    for (int t = 0; t < 2; ++t) {
      // S = K^T Q (rows=keys, cols=queries), log2 domain
      f32x4 s[4];
#pragma unroll
      for (int ktl = 0; ktl < 4; ++ktl) {
        f32x4 z = {0, 0, 0, 0};
        z = __builtin_amdgcn_mfma_f32_16x16x32_bf16(ak[ktl][0], bq[t][0], z, 0, 0, 0);
        z = __builtin_amdgcn_mfma_f32_16x16x32_bf16(ak[ktl][1], bq[t][1], z, 0, 0, 0);
        s[ktl] = z;
      }
      // p = 2^s; write P[q=l16][key] to wave-private scratch (16 rows)
      u16* Pq = &Pw[l16 * LP];
#pragma unroll
      for (int ktl = 0; ktl < 4; ++ktl) {
        float p0 = EXP2F(s[ktl][0]);
        float p1 = EXP2F(s[ktl][1]);
        float p2 = EXP2F(s[ktl][2]);
        float p3 = EXP2F(s[ktl][3]);
        l_part[t] += p0 + p1 + p2 + p3;
        *(u32*)&Pq[ktl * 16 + quad * 4] = pk2(p0, p1);
        *(u32*)&Pq[ktl * 16 + quad * 4 + 2] = pk2(p2, p3);
      }
      // O += V * P
#pragma unroll
      for (int kh = 0; kh < 2; ++kh) {
        bf16x8 bp = ld_bf8(&Pq[kh * 32 + quad * 8]);
#pragma unroll
        for (int ct = 0; ct < 4; ++ct)
          o[t][ct] = __builtin_amdgcn_mfma_f32_16x16x32_bf16(av[ct][kh], bp, o[t][ct], 0, 0, 0);
      }
    }
  }
#undef LOADKV

  // final l reduction + epilogue per sub-tile (OT reuses wave scratch)
  float* ob = outg + ((size_t)b * NC) * NL;
#pragma unroll
  for (int t = 0; t < 2; ++t) {
    float lp = l_part[t];
    lp += __shfl_xor(lp, 16);
    lp += __shfl_xor(lp, 32);
    float rinv = 1.0f / lp;
    u16* OT = &Pw[l16 * LP];
    *(u32*)&OT[ 0 + quad * 4]     = pk2(o[t][0][0]*rinv, o[t][0][1]*rinv);
    *(u32*)&OT[ 0 + quad * 4 + 2] = pk2(o[t][0][2]*rinv, o[t][0][3]*rinv);
    *(u32*)&OT[16 + quad * 4]     = pk2(o[t][1][0]*rinv, o[t][1][1]*rinv);
    *(u32*)&OT[16 + quad * 4 + 2] = pk2(o[t][1][2]*rinv, o[t][1][3]*rinv);
    *(u32*)&OT[32 + quad * 4]     = pk2(o[t][2][0]*rinv, o[t][2][1]*rinv);
    *(u32*)&OT[32 + quad * 4 + 2] = pk2(o[t][2][2]*rinv, o[t][2][3]*rinv);
    *(u32*)&OT[48 + quad * 4]     = pk2(o[t][3][0]*rinv, o[t][3][1]*rinv);
    *(u32*)&OT[48 + quad * 4 + 2] = pk2(o[t][3][2]*rinv, o[t][3][3]*rinv);

    int qcol = q0 + wave * 32 + t * 16 + l16;
#pragma unroll
    for (int mt = 0; mt < 4; ++mt) {
      f32x4 acc = {0, 0, 0, 0};
#pragma unroll
      for (int kh = 0; kh < 2; ++kh) {
        bf16x8 a = ld_bf8(&UW[(mt * 16 + l16) * LP + kh * 32 + quad * 8]);
        bf16x8 bt = ld_bf8(&OT[kh * 32 + quad * 8]);
        acc = __builtin_amdgcn_mfma_f32_16x16x32_bf16(a, bt, acc, 0, 0, 0);
      }
#pragma unroll
      for (int rr = 0; rr < 4; ++rr) {
        int c = mt * 16 + quad * 4 + rr;
        atomicAdd(&ob[(size_t)c * NL + qcol], acc[rr]);
      }
    }
  }
}

// ---------------------------------------------------------------------------
extern "C" void kernel_launch(void* const* d_in, const int* in_sizes, int n_in,
                              void* d_out, int out_size, void* d_ws, size_t ws_size,
                              hipStream_t stream) {
  (void)in_sizes; (void)n_in; (void)out_size; (void)ws_size;
  const float* x   = (const float*)d_in[0];
  const float* qdw = (const float*)d_in[1];
  const float* qdb = (const float*)d_in[2];
  const float* qpw = (const float*)d_in[3];
  const float* qpb = (const float*)d_in[4];
  const float* kdw = (const float*)d_in[5];
  const float* kdb = (const float*)d_in[6];
  const float* kpw = (const float*)d_in[7];
  const float* kpb = (const float*)d_in[8];
  const float* vdw = (const float*)d_in[9];
  const float* vdb = (const float*)d_in[10];
  const float* vpw = (const float*)d_in[11];
  const float* vpb = (const float*)d_in[12];
  const float* uw  = (const float*)d_in[13];
  const float* ub  = (const float*)d_in[14];

  char* ws = (char*)d_ws;
  u16*   xT  = (u16*)(ws + XT_OFF);
  u16*   Wm  = (u16*)(ws + WM_OFF);
  float* pbm = (float*)(ws + PBM_OFF);
  u16*   v   = (u16*)(ws + V_OFF);
  u16*   qT  = (u16*)(ws + QT_OFF);
  u16*   kT  = (u16*)(ws + KT_OFF);
  float* out = (float*)d_out;

  prep_all<<<1030, 256, 0, stream>>>(
      x, qdw, qdb, qpw, qpb, kdw, kdb, kpw, kpb, vdw, vdb, vpw, vpb,
      ub, Wm, pbm, xT, out);
  qkv_gemm<<<768, 256, 0, stream>>>(xT, Wm, pbm, v, qT, kT);
  attn_kernel<<<512, 128, 0, stream>>>(qT, kT, v, uw, out, 0);
  attn_kernel<<<512, 128, 0, stream>>>(qT, kT, v, uw, out, 16);
}

// Round 10
// 164.350 us; speedup vs baseline: 2.6393x; 2.6393x over previous
//
#include <hip/hip_runtime.h>
#include <hip/hip_bf16.h>
#include <stdint.h>
#include <string.h>

typedef unsigned short u16;
typedef unsigned int u32;
typedef __bf16 bf16x8 __attribute__((ext_vector_type(8)));
typedef float f32x4 __attribute__((ext_vector_type(4)));

// Problem constants
#define NB 4
#define NC 64
#define NH 8
#define NL 2048
#define HC 512   // H*C

// Workspace layout (bytes).
#define XT_OFF  ((size_t)0)          // bf16 xT[b][l][c]            1 MB
#define WM_OFF  ((size_t)1 << 20)    // bf16 Wm[tns][d][o][c]       576 KB
#define PBM_OFF ((size_t)2 << 20)    // f32  pbm[tns][o]            6 KB
#define V_OFF   ((size_t)4 << 20)    // bf16 v[b][o][l]             8 MB
#define QT_OFF  ((size_t)12 << 20)   // bf16 qT[bh][l][c]           8 MB
#define KT_OFF  ((size_t)20 << 20)   // bf16 kT[bh][l][c]           8 MB

#define LP 68   // padded LDS row stride (u16); measured 0 bank conflicts (R8)

#if __has_builtin(__builtin_amdgcn_exp2f)
#define EXP2F __builtin_amdgcn_exp2f
#else
#define EXP2F exp2f
#endif

static __device__ __forceinline__ u16 f2bfu(float f) {
  union { float f; unsigned int i; } x; x.f = f;
  unsigned int i = x.i;
  return (u16)((i + 0x7fffu + ((i >> 16) & 1u)) >> 16);  // RTE, finite inputs
}
static __device__ __forceinline__ u32 pk2(float a, float b) {
  float2 f; f.x = a; f.y = b;
  __hip_bfloat162 h = __float22bfloat162_rn(f);   // packed cvt on gfx950
  u32 w; __builtin_memcpy(&w, &h, 4); return w;
}
static __device__ __forceinline__ bf16x8 ld_bf8(const u16* p) {
  bf16x8 v; __builtin_memcpy(&v, p, 16); return v;
}

// ---------------------------------------------------------------------------
// Kernel P: fused prep. Block ranges:
//  [0,512)    init_out: out[b,c,l] = ub[c]
//  [512,902)  prep_w: merged conv weights + folded bias
//  [902,1030) prep_x: x[b][c][l] f32 -> xT[b][l][c] bf16
// ---------------------------------------------------------------------------
__global__ __launch_bounds__(256) void prep_all(
    const float* __restrict__ x,
    const float* __restrict__ qdw, const float* __restrict__ qdb,
    const float* __restrict__ qpw, const float* __restrict__ qpb,
    const float* __restrict__ kdw, const float* __restrict__ kdb,
    const float* __restrict__ kpw, const float* __restrict__ kpb,
    const float* __restrict__ vdw, const float* __restrict__ vdb,
    const float* __restrict__ vpw, const float* __restrict__ vpb,
    const float* __restrict__ ub,
    u16* __restrict__ Wm, float* __restrict__ pbm,
    u16* __restrict__ xT, float* __restrict__ out)
{
  __shared__ __align__(16) u16 T[64 * LP];
  int bx = blockIdx.x;
  int tid = threadIdx.x;

  if (bx < 512) {
    int i4 = bx * 256 + tid;     // float4 index
    int c = (i4 >> 9) & 63;
    float f = ub[c];
    float4 v = {f, f, f, f};
    ((float4*)out)[i4] = v;
    return;
  }
  if (bx < 902) {
    int idx = (bx - 512) * 256 + tid;
    if (idx < 98304) {
      int tns = idx >> 15, r = idx & 32767, o = r >> 6, c = r & 63;
      const float* dw = (tns == 0) ? qdw : (tns == 1) ? kdw : vdw;
      const float* pw = (tns == 0) ? qpw : (tns == 1) ? kpw : vpw;
      float s = (tns == 0) ? 0.35355339059327373f * 1.4426950408889634f
              : (tns == 1) ? 0.35355339059327373f : 1.0f;
      float w = pw[o * 64 + c] * s;
#pragma unroll
      for (int d = 0; d < 3; ++d)
        Wm[((size_t)(tns * 3 + d) * 512 + o) * 64 + c] = f2bfu(w * dw[c * 3 + d]);
    } else {
      int i = idx - 98304;
      int tns = i >> 9, o = i & 511;
      const float* db = (tns == 0) ? qdb : (tns == 1) ? kdb : vdb;
      const float* pw = (tns == 0) ? qpw : (tns == 1) ? kpw : vpw;
      const float* pb = (tns == 0) ? qpb : (tns == 1) ? kpb : vpb;
      float s = (tns == 0) ? 0.35355339059327373f * 1.4426950408889634f
              : (tns == 1) ? 0.35355339059327373f : 1.0f;
      float bias = pb[o];
      for (int c = 0; c < 64; ++c) bias += pw[o * 64 + c] * db[c];
      pbm[i] = bias * s;
    }
    return;
  }
  // prep_x
  {
    int b2 = bx - 902;
    int lt = b2 & 31, b = b2 >> 5;
    {
      int c = tid & 63, ls = (tid >> 6) * 16;
      const float4* g = (const float4*)(x + ((size_t)b * NC + c) * NL + lt * 64 + ls);
      u16 tmp[16];
#pragma unroll
      for (int j4 = 0; j4 < 4; ++j4) {
        float4 f = g[j4];
        tmp[j4*4+0] = f2bfu(f.x); tmp[j4*4+1] = f2bfu(f.y);
        tmp[j4*4+2] = f2bfu(f.z); tmp[j4*4+3] = f2bfu(f.w);
      }
#pragma unroll
      for (int j = 0; j < 16; ++j) T[(ls + j) * LP + c] = tmp[j];
    }
    __syncthreads();
    {
      int r = tid >> 2, cs = (tid & 3) * 16;
      uint4 a = *(const uint4*)&T[r * LP + cs];
      uint4 b3 = *(const uint4*)&T[r * LP + cs + 8];
      u16* o = xT + ((size_t)b * NL + lt * 64 + r) * 64 + cs;
      *(uint4*)o = a;
      *(uint4*)(o + 8) = b3;
    }
  }
}

// ---------------------------------------------------------------------------
// Kernel 1: qkv via MFMA, 4 l-tiles per block, XS double-buffered, ONE
// barrier per tile (epilogue rows are wave-private -> no cross-wave hazard).
// grid = 4b * 3tns * 8och * 8 lgroups = 768 blocks; LDS ~53 KB -> 3/CU.
// ---------------------------------------------------------------------------
__global__ __launch_bounds__(256) void qkv_gemm(
    const u16* __restrict__ xT, const u16* __restrict__ Wm,
    const float* __restrict__ pbm,
    u16* __restrict__ v, u16* __restrict__ qT, u16* __restrict__ kT)
{
  __shared__ __align__(16) u16 WS[3][64 * LP];   // WS[d][o][c]
  __shared__ __align__(16) u16 XS[2][66 * LP];   // XS[buf][r][c], r0 = l0-1
  __shared__ __align__(16) u16 OS[64 * LP];      // epilogue staging (wave-private rows)

  int bx = blockIdx.x;
  int lg  = bx & 7;
  int och = (bx >> 3) & 7;
  int tmp = bx >> 6;
  int tns = tmp % 3;
  int b   = tmp / 3;

  int tid = threadIdx.x;
  int wave = tid >> 6, lane = tid & 63, quad = lane >> 4, l16 = lane & 15;
  const u16* xg = xT + (size_t)b * NL * 64;

  // stage merged weights once (o-chunk slice, 3 d-slices)
  {
    const u16* wg = Wm + ((size_t)(tns * 3) * 512 + och * 64) * 64;
#pragma unroll
    for (int it = 0; it < 6; ++it) {
      int s = tid + it * 256;
      int d = s >> 9, r = s & 511;
      int o = r >> 3, c4 = r & 7;
      uint4 w = *(const uint4*)(wg + ((size_t)d * 512 + o) * 64 + c4 * 8);
      *(uint4*)&WS[d][o * LP + c4 * 8] = w;
    }
  }

  // XS prefetch helpers: 528 uint4 slots (66 rows x 8), <=3 per thread
  int xr0 = tid >> 3,          xc0 = (tid & 7) * 8;
  int xr1 = (tid + 256) >> 3,  xc1 = xc0;
  int xr2 = (tid + 512) >> 3,  xc2 = xc0;
  uint4 R0, R1, R2;
  uint4 Z = {0, 0, 0, 0};

#define LOAD_XS(tt)                                                         \
  {                                                                         \
    int base = (lg * 4 + (tt)) * 64 - 1;                                    \
    int g0 = base + xr0, g1 = base + xr1, g2 = base + xr2;                  \
    R0 = ((unsigned)g0 < NL) ? *(const uint4*)(xg + (size_t)g0 * 64 + xc0) : Z; \
    R1 = ((unsigned)g1 < NL) ? *(const uint4*)(xg + (size_t)g1 * 64 + xc1) : Z; \
    if (tid < 16)                                                           \
      R2 = ((unsigned)g2 < NL) ? *(const uint4*)(xg + (size_t)g2 * 64 + xc2) : Z; \
  }
#define STORE_XS(bf)                                                        \
  {                                                                         \
    *(uint4*)&XS[bf][xr0 * LP + xc0] = R0;                                  \
    *(uint4*)&XS[bf][xr1 * LP + xc1] = R1;                                  \
    if (tid < 16) *(uint4*)&XS[bf][xr2 * LP + xc2] = R2;                    \
  }

  LOAD_XS(0); STORE_XS(0);
  LOAD_XS(1);
  __syncthreads();

  // bias regs + v-path hoisted A fragments (tile-invariant)
  float bias4[4];
  bf16x8 aw[3][2];
  if (tns == 2) {
    const float* pbt = pbm + tns * 512 + och * 64 + wave * 16;
#pragma unroll
    for (int rr = 0; rr < 4; ++rr) bias4[rr] = pbt[quad * 4 + rr];
#pragma unroll
    for (int d = 0; d < 3; ++d)
#pragma unroll
      for (int kh = 0; kh < 2; ++kh)
        aw[d][kh] = ld_bf8(&WS[d][(wave * 16 + l16) * LP + kh * 32 + quad * 8]);
  } else {
    const float* pbt = pbm + tns * 512 + och * 64;
#pragma unroll
    for (int nt = 0; nt < 4; ++nt) bias4[nt] = pbt[nt * 16 + l16];
  }

  for (int t = 0; t < 4; ++t) {
    int cur = t & 1;
    f32x4 acc[4] = {{0,0,0,0},{0,0,0,0},{0,0,0,0},{0,0,0,0}};

    if (tns == 2) {
#pragma unroll
      for (int nt = 0; nt < 4; ++nt)
#pragma unroll
        for (int d = 0; d < 3; ++d)
#pragma unroll
          for (int kh = 0; kh < 2; ++kh) {
            bf16x8 bx8 = ld_bf8(&XS[cur][(nt * 16 + l16 + d) * LP + kh * 32 + quad * 8]);
            acc[nt] = __builtin_amdgcn_mfma_f32_16x16x32_bf16(aw[d][kh], bx8, acc[nt], 0, 0, 0);
          }
    } else {
      bf16x8 ax[3][2];
#pragma unroll
      for (int d = 0; d < 3; ++d)
#pragma unroll
        for (int kh = 0; kh < 2; ++kh)
          ax[d][kh] = ld_bf8(&XS[cur][(wave * 16 + l16 + d) * LP + kh * 32 + quad * 8]);
#pragma unroll
      for (int nt = 0; nt < 4; ++nt)
#pragma unroll
        for (int d = 0; d < 3; ++d)
#pragma unroll
          for (int kh = 0; kh < 2; ++kh) {
            bf16x8 bw = ld_bf8(&WS[d][(nt * 16 + l16) * LP + kh * 32 + quad * 8]);
            acc[nt] = __builtin_amdgcn_mfma_f32_16x16x32_bf16(ax[d][kh], bw, acc[nt], 0, 0, 0);
          }
    }

    if (t < 3) { STORE_XS((t + 1) & 1); if (t < 2) LOAD_XS(t + 2); }
    __syncthreads();   // the ONLY barrier per tile: XS[next] ready

    // epilogue: wave-private OS rows -> intra-wave ordering, no barrier.
    if (tns == 2) {
#pragma unroll
      for (int nt = 0; nt < 4; ++nt)
#pragma unroll
        for (int rr = 0; rr < 4; ++rr)
          OS[(wave * 16 + quad * 4 + rr) * LP + nt * 16 + l16] =
              f2bfu(acc[nt][rr] + bias4[rr]);
    } else {
#pragma unroll
      for (int nt = 0; nt < 4; ++nt)
#pragma unroll
        for (int rr = 0; rr < 4; ++rr)
          OS[(wave * 16 + quad * 4 + rr) * LP + nt * 16 + l16] =
              f2bfu(acc[nt][rr] + bias4[nt]);
    }

    // coalesced store of this wave's own 16 rows: 4 lanes per row, 2 uint4
    {
      int lt = lg * 4 + t;
      int r = wave * 16 + (lane >> 2), ck = (lane & 3) * 16;
      uint4 a = *(const uint4*)&OS[r * LP + ck];
      uint4 b2 = *(const uint4*)&OS[r * LP + ck + 8];
      u16* gp;
      if (tns == 2)
        gp = v + ((size_t)(b * HC + och * 64 + r)) * NL + lt * 64 + ck;
      else {
        u16* dst = (tns == 0) ? qT : kT;
        gp = dst + ((size_t)(b * 8 + och) * NL + lt * 64 + r) * 64 + ck;
      }
      *(uint4*)gp = a;
      *(uint4*)(gp + 8) = b2;
    }
  }
#undef LOAD_XS
#undef STORE_XS
}

// ---------------------------------------------------------------------------
// Kernel 2: flash attention + fused unify. R7 structure restored (R9's
// 2-wave blocks = 1 wave/SIMD = no latency hiding -> 2.6x regression).
// 512 blocks x 256 thr, 4 waves x 32q. Single K/V buffer, 2 barriers/iter.
// XCD swizzle: bh = bx&31 -> same-bh q-tile blocks sit 32 apart = same XCD
// under mod-8 round-robin; per-XCD K/V working set 4 heads x 512KB = 2MB
// fits the 4MB XCD L2 (FETCH was 70MB vs 24MB compulsory = cross-XCD
// re-fetch; attn is fetch-stream-bound at 1.3TB/s).
// Q fragments straight from global (R9-verified); LDS 34.8 KB.
// ---------------------------------------------------------------------------
__global__ __launch_bounds__(256) void attn_kernel(
    const u16* __restrict__ qT, const u16* __restrict__ kT,
    const u16* __restrict__ vg, const float* __restrict__ uw,
    float* __restrict__ outg)
{
  __shared__ __align__(16) u16 Kt[64 * LP];      // Kt[key][c]
  __shared__ __align__(16) u16 Vt[64 * LP];      // Vt[c][key]
  __shared__ __align__(16) u16 UW[64 * LP];      // UW[c][c']
  __shared__ __align__(16) u16 PB[4][16 * LP];   // per-wave P / OT scratch

  int bx = blockIdx.x;
  int bh = bx & 31, qt = bx >> 5;    // XCD swizzle (see header comment)
  int b = bh >> 3, h = bh & 7;
  int tid = threadIdx.x;
  int wave = tid >> 6, lane = tid & 63, quad = lane >> 4, l16 = lane & 15;

  const u16* Qh = qT + (size_t)bh * NL * 64;
  const u16* Kh = kT + (size_t)bh * NL * 64;
  const u16* Vh = vg + ((size_t)(b * HC + h * NC)) * NL;
  int q0 = qt * 128;

  int sr = tid >> 2, ss = (tid & 3) * 16;   // K staging: row, u16-col
  int vc = tid & 63, vk = (tid >> 6) * 16;  // V staging: c row, key seg

  // stage UW head slice as bf16: UW[c][c'] = uw[c*512 + h*64 + c']
  {
    int c = tid >> 2, g = (tid & 3) * 16;
    const float4* s = (const float4*)(uw + (size_t)c * HC + h * 64 + g);
#pragma unroll
    for (int j = 0; j < 4; ++j) {
      float4 w = s[j];
      u16* d = &UW[c * LP + g + j * 4];
      d[0] = f2bfu(w.x); d[1] = f2bfu(w.y); d[2] = f2bfu(w.z); d[3] = f2bfu(w.w);
    }
  }

  // Q fragments for this wave's 32 queries, straight from global (qT[l][c])
  bf16x8 bq[2][2];
#pragma unroll
  for (int t = 0; t < 2; ++t)
#pragma unroll
    for (int kh = 0; kh < 2; ++kh)
      bq[t][kh] = ld_bf8(Qh + (size_t)(q0 + wave * 32 + t * 16 + l16) * 64
                         + kh * 32 + quad * 8);

  f32x4 o[2][4];
#pragma unroll
  for (int t = 0; t < 2; ++t)
#pragma unroll
    for (int ct = 0; ct < 4; ++ct) o[t][ct] = (f32x4){0, 0, 0, 0};
  float l_part[2] = {0.f, 0.f};

  // prefetch iter 0 K/V into registers
  uint4 ka, kb, va, vb;
  {
    const u16* ks = Kh + (size_t)sr * 64 + ss;
    ka = *(const uint4*)ks; kb = *(const uint4*)(ks + 8);
    const u16* vs = Vh + (size_t)vc * NL + vk;
    va = *(const uint4*)vs; vb = *(const uint4*)(vs + 8);
  }
  __syncthreads();   // UW staged

  u16* Pw = &PB[wave][0];

  for (int i = 0; i < 32; ++i) {
    *(uint4*)&Kt[sr * LP + ss] = ka;
    *(uint4*)&Kt[sr * LP + ss + 8] = kb;
    *(uint4*)&Vt[vc * LP + vk] = va;
    *(uint4*)&Vt[vc * LP + vk + 8] = vb;
    __syncthreads();
    if (i < 31) {   // prefetch next iter; overlaps compute
      int kt1 = (i + 1) * 64;
      const u16* ks = Kh + (size_t)(kt1 + sr) * 64 + ss;
      ka = *(const uint4*)ks; kb = *(const uint4*)(ks + 8);
      const u16* vs = Vh + (size_t)vc * NL + kt1 + vk;
      va = *(const uint4*)vs; vb = *(const uint4*)(vs + 8);
    }

    // K and V fragments once per wave (reused for both q sub-tiles)
    bf16x8 ak[4][2], av[4][2];
#pragma unroll
    for (int j = 0; j < 4; ++j)
#pragma unroll
      for (int kh = 0; kh < 2; ++kh) {
        ak[j][kh] = ld_bf8(&Kt[(j * 16 + l16) * LP + kh * 32 + quad * 8]);
        av[j][kh] = ld_bf8(&Vt[(j * 16 + l16) * LP + kh * 32 + quad * 8]);
      }

#pragma unroll
    for (int t = 0; t < 2; ++t) {
      // S = K^T Q (rows=keys, cols=queries), log2 domain
      f32x4 s[4];
#pragma unroll
      for (int ktl = 0; ktl < 4; ++ktl) {
        f32x4 z = {0, 0, 0, 0};
        z = __builtin_amdgcn_mfma_f32_16x16x32_bf16(ak[ktl][0], bq[t][0], z, 0, 0, 0);
        z = __builtin_amdgcn_mfma_f32_16x16x32_bf16(ak[ktl][1], bq[t][1], z, 0, 0, 0);
        s[ktl] = z;
      }
      // p = 2^s; write P[q=l16][key] to wave-private scratch (16 rows)
      u16* Pq = &Pw[l16 * LP];
#pragma unroll
      for (int ktl = 0; ktl < 4; ++ktl) {
        float p0 = EXP2F(s[ktl][0]);
        float p1 = EXP2F(s[ktl][1]);
        float p2 = EXP2F(s[ktl][2]);
        float p3 = EXP2F(s[ktl][3]);
        l_part[t] += p0 + p1 + p2 + p3;
        *(u32*)&Pq[ktl * 16 + quad * 4] = pk2(p0, p1);
        *(u32*)&Pq[ktl * 16 + quad * 4 + 2] = pk2(p2, p3);
      }
      // O += V * P
#pragma unroll
      for (int kh = 0; kh < 2; ++kh) {
        bf16x8 bp = ld_bf8(&Pq[kh * 32 + quad * 8]);
#pragma unroll
        for (int ct = 0; ct < 4; ++ct)
          o[t][ct] = __builtin_amdgcn_mfma_f32_16x16x32_bf16(av[ct][kh], bp, o[t][ct], 0, 0, 0);
      }
    }
    __syncthreads();   // all waves done reading Kt/Vt before next overwrite
  }

  // final l reduction + epilogue per sub-tile (OT reuses wave scratch)
  float* ob = outg + ((size_t)b * NC) * NL;
#pragma unroll
  for (int t = 0; t < 2; ++t) {
    float lp = l_part[t];
    lp += __shfl_xor(lp, 16);
    lp += __shfl_xor(lp, 32);
    float rinv = 1.0f / lp;
    u16* OT = &Pw[l16 * LP];
    *(u32*)&OT[ 0 + quad * 4]     = pk2(o[t][0][0]*rinv, o[t][0][1]*rinv);
    *(u32*)&OT[ 0 + quad * 4 + 2] = pk2(o[t][0][2]*rinv, o[t][0][3]*rinv);
    *(u32*)&OT[16 + quad * 4]     = pk2(o[t][1][0]*rinv, o[t][1][1]*rinv);
    *(u32*)&OT[16 + quad * 4 + 2] = pk2(o[t][1][2]*rinv, o[t][1][3]*rinv);
    *(u32*)&OT[32 + quad * 4]     = pk2(o[t][2][0]*rinv, o[t][2][1]*rinv);
    *(u32*)&OT[32 + quad * 4 + 2] = pk2(o[t][2][2]*rinv, o[t][2][3]*rinv);
    *(u32*)&OT[48 + quad * 4]     = pk2(o[t][3][0]*rinv, o[t][3][1]*rinv);
    *(u32*)&OT[48 + quad * 4 + 2] = pk2(o[t][3][2]*rinv, o[t][3][3]*rinv);

    int qcol = q0 + wave * 32 + t * 16 + l16;
#pragma unroll
    for (int mt = 0; mt < 4; ++mt) {
      f32x4 acc = {0, 0, 0, 0};
#pragma unroll
      for (int kh = 0; kh < 2; ++kh) {
        bf16x8 a = ld_bf8(&UW[(mt * 16 + l16) * LP + kh * 32 + quad * 8]);
        bf16x8 bt = ld_bf8(&OT[kh * 32 + quad * 8]);
        acc = __builtin_amdgcn_mfma_f32_16x16x32_bf16(a, bt, acc, 0, 0, 0);
      }
#pragma unroll
      for (int rr = 0; rr < 4; ++rr) {
        int c = mt * 16 + quad * 4 + rr;
        atomicAdd(&ob[(size_t)c * NL + qcol], acc[rr]);
      }
    }
  }
}

// ---------------------------------------------------------------------------
extern "C" void kernel_launch(void* const* d_in, const int* in_sizes, int n_in,
                              void* d_out, int out_size, void* d_ws, size_t ws_size,
                              hipStream_t stream) {
  (void)in_sizes; (void)n_in; (void)out_size; (void)ws_size;
  const float* x   = (const float*)d_in[0];
  const float* qdw = (const float*)d_in[1];
  const float* qdb = (const float*)d_in[2];
  const float* qpw = (const float*)d_in[3];
  const float* qpb = (const float*)d_in[4];
  const float* kdw = (const float*)d_in[5];
  const float* kdb = (const float*)d_in[6];
  const float* kpw = (const float*)d_in[7];
  const float* kpb = (const float*)d_in[8];
  const float* vdw = (const float*)d_in[9];
  const float* vdb = (const float*)d_in[10];
  const float* vpw = (const float*)d_in[11];
  const float* vpb = (const float*)d_in[12];
  const float* uw  = (const float*)d_in[13];
  const float* ub  = (const float*)d_in[14];

  char* ws = (char*)d_ws;
  u16*   xT  = (u16*)(ws + XT_OFF);
  u16*   Wm  = (u16*)(ws + WM_OFF);
  float* pbm = (float*)(ws + PBM_OFF);
  u16*   v   = (u16*)(ws + V_OFF);
  u16*   qT  = (u16*)(ws + QT_OFF);
  u16*   kT  = (u16*)(ws + KT_OFF);
  float* out = (float*)d_out;

  prep_all<<<1030, 256, 0, stream>>>(
      x, qdw, qdb, qpw, qpb, kdw, kdb, kpw, kpb, vdw, vdb, vpw, vpb,
      ub, Wm, pbm, xT, out);
  qkv_gemm<<<768, 256, 0, stream>>>(xT, Wm, pbm, v, qT, kT);
  attn_kernel<<<512, 256, 0, stream>>>(qT, kT, v, uw, out);
}